// Round 3
// baseline (154.459 us; speedup 1.0000x reference)
//
#include <hip/hip_runtime.h>

// Bidirectional LSTM, B=16384 T=512 I=1 H=8, + final linear on [h_f(T-1), h_b(T-1)].
// Backward direction's state at time T-1 is its FIRST scan step -> one step only.
//
// R3: 8 lanes/element (R1 decomposition, which was VALU-issue-bound at 80%+):
//  - gate activations sigma(i),sigma(f),tanh(g),sigma(o) via a 1024-segment
//    piecewise-linear LUT in LDS (ds_read_b64 gather). Table coordinate
//    u = 32*z+512 (64*z+512 for tanh arg) is folded into pre-scaled weights,
//    so the dot product directly produces the table coordinate.
//  - tanh(c) stays exp-based (lower latency than LDS on the serial c->h path).
//  - gate dots via v_pk_fma_f32 (packed fp32, 2 FMA/instr), paired along K so
//    swizzled h broadcasts drop straight into register pairs.

typedef float f32x2 __attribute__((ext_vector_type(2)));

#define LOG2E 1.4426950408889634f

// Broadcast lane ((i & ~7) | k)'s value to all lanes of each 8-lane group.
#define BCAST8(v, k) __int_as_float(__builtin_amdgcn_ds_swizzle(__float_as_int(v), (((k) << 5) | 0x18)))

__device__ __forceinline__ f32x2 pk_mul(f32x2 a, f32x2 b) {
    f32x2 d;
    asm("v_pk_mul_f32 %0, %1, %2" : "=v"(d) : "v"(a), "v"(b));
    return d;
}
__device__ __forceinline__ f32x2 pk_fma(f32x2 a, f32x2 b, f32x2 c) {
    asm("v_pk_fma_f32 %0, %1, %2, %0" : "+v"(c) : "v"(a), "v"(b));
    return c;
}

// PWL sigmoid lookup. u is the table coordinate (= 32x+512); entry = {slope, intercept}.
__device__ __forceinline__ float lut_sig(const float2* __restrict__ t, float u) {
    float uc = __builtin_amdgcn_fmed3f(u, 0.0f, 1023.0f);
    int i = (int)uc;
    float2 si = t[i];
    return fmaf(si.x, uc, si.y);
}

struct Ctx {
    f32x2 wk[4][4];   // [row r=i,f,g,o][k-pair p]: {W'[r][2p], W'[r][2p+1]} (pre-scaled)
    f32x2 wxb[4];     // {wx'[r], b'[r]}  (z-init via pk_mul with {x, 1})
};

__device__ __forceinline__ void load_ctx(Ctx& C, int j,
    const float* __restrict__ w_ih, const float* __restrict__ w_hh,
    const float* __restrict__ b)
{
    const float sc[4] = {32.0f, 32.0f, 64.0f, 32.0f};  // sigmoid rows x32, tanh row x64
    const int rows[4] = {j, 8 + j, 16 + j, 24 + j};
#pragma unroll
    for (int r = 0; r < 4; ++r) {
        int row = rows[r];
        float s = sc[r];
        const float4* wr = (const float4*)(w_hh + row * 8);
        float4 a = wr[0], q = wr[1];
        C.wk[r][0] = f32x2{a.x * s, a.y * s};
        C.wk[r][1] = f32x2{a.z * s, a.w * s};
        C.wk[r][2] = f32x2{q.x * s, q.y * s};
        C.wk[r][3] = f32x2{q.z * s, q.w * s};
        C.wxb[r] = f32x2{w_ih[row] * s, fmaf(b[row], s, 512.0f)};
    }
}

__device__ __forceinline__ void lstm_step(float xt, float& h, float& c,
                                          const Ctx& C, const float2* __restrict__ tab)
{
    // broadcast h of the 8-lane group into k-pairs (swizzle results land in pairs)
    f32x2 hp[4];
    hp[0][0] = BCAST8(h, 0); hp[0][1] = BCAST8(h, 1);
    hp[1][0] = BCAST8(h, 2); hp[1][1] = BCAST8(h, 3);
    hp[2][0] = BCAST8(h, 4); hp[2][1] = BCAST8(h, 5);
    hp[3][0] = BCAST8(h, 6); hp[3][1] = BCAST8(h, 7);

    f32x2 xp = f32x2{xt, 1.0f};
    f32x2 acc0 = pk_mul(xp, C.wxb[0]);
    f32x2 acc1 = pk_mul(xp, C.wxb[1]);
    f32x2 acc2 = pk_mul(xp, C.wxb[2]);
    f32x2 acc3 = pk_mul(xp, C.wxb[3]);
#pragma unroll
    for (int p = 0; p < 4; ++p) {
        acc0 = pk_fma(hp[p], C.wk[0][p], acc0);
        acc1 = pk_fma(hp[p], C.wk[1][p], acc1);
        acc2 = pk_fma(hp[p], C.wk[2][p], acc2);
        acc3 = pk_fma(hp[p], C.wk[3][p], acc3);
    }
    float ui = acc0[0] + acc0[1];
    float uf = acc1[0] + acc1[1];
    float ug = acc2[0] + acc2[1];
    float uo = acc3[0] + acc3[1];

    float si = lut_sig(tab, ui);
    float sf = lut_sig(tab, uf);
    float sg = lut_sig(tab, ug);   // sigma(2g)
    float so = lut_sig(tab, uo);

    float tg = fmaf(2.0f, sg, -1.0f);          // tanh(g)
    c = fmaf(sf, c, si * tg);
    // tanh(c) = 1 - 2/(1+exp2(2c*log2e)); exact limits at +-inf.
    float e = __builtin_amdgcn_exp2f(c * (2.0f * LOG2E));
    float tc = fmaf(-2.0f, __builtin_amdgcn_rcpf(1.0f + e), 1.0f);
    h = so * tc;
}

__global__ __launch_bounds__(256, 2) void bilstm_kernel(
    const float* __restrict__ x, const float* __restrict__ h0, const float* __restrict__ c0,
    const float* __restrict__ w_ih_f, const float* __restrict__ w_hh_f, const float* __restrict__ b_f,
    const float* __restrict__ w_ih_b, const float* __restrict__ w_hh_b, const float* __restrict__ b_b,
    const float* __restrict__ w_lin, const float* __restrict__ b_lin,
    float* __restrict__ out, int B, int T)
{
    __shared__ float2 tab[1024];
    // Build PWL sigmoid table: node i at x = (i-512)/32, f(u) = slope*u + intercept.
    for (int i = threadIdx.x; i < 1024; i += 256) {
        float x0 = (i - 512) * (1.0f / 32.0f);
        float x1 = (i - 511) * (1.0f / 32.0f);
        float s0 = 1.0f / (1.0f + __expf(-x0));
        float s1 = 1.0f / (1.0f + __expf(-x1));
        float slope = s1 - s0;  // per index unit
        tab[i] = make_float2(slope, fmaf(-slope, (float)i, s0));
    }
    __syncthreads();

    int tid = blockIdx.x * 256 + threadIdx.x;
    int b = tid >> 3;
    int j = tid & 7;
    if (b >= B) return;

    Ctx Cf;
    load_ctx(Cf, j, w_ih_f, w_hh_f, b_f);

    float h = h0[(size_t)b * 8 + j];
    float c = c0[(size_t)b * 8 + j];

    const float4* xr = (const float4*)(x + (size_t)b * T);
    int nT4 = T >> 2;
    for (int t4 = 0; t4 < nT4; ++t4) {
        float4 xv = xr[t4];
        lstm_step(xv.x, h, c, Cf, tab);
        lstm_step(xv.y, h, c, Cf, tab);
        lstm_step(xv.z, h, c, Cf, tab);
        lstm_step(xv.w, h, c, Cf, tab);
    }

    // backward direction: exactly one step on x[:, T-1]
    Ctx Cb;
    load_ctx(Cb, j, w_ih_b, w_hh_b, b_b);
    float hb = h0[(size_t)B * 8 + (size_t)b * 8 + j];
    float cb = c0[(size_t)B * 8 + (size_t)b * 8 + j];
    float xlast = x[(size_t)b * T + (T - 1)];
    lstm_step(xlast, hb, cb, Cb, tab);

    // final linear: out[b] = sum_j h[j]*wl[j] + hb[j]*wl[8+j] + b_lin
    float part = fmaf(h, w_lin[j], hb * w_lin[8 + j]);
    part += __shfl_xor(part, 1, 8);
    part += __shfl_xor(part, 2, 8);
    part += __shfl_xor(part, 4, 8);
    if (j == 0) out[b] = part + b_lin[0];
}

extern "C" void kernel_launch(void* const* d_in, const int* in_sizes, int n_in,
                              void* d_out, int out_size, void* d_ws, size_t ws_size,
                              hipStream_t stream)
{
    const float* x      = (const float*)d_in[0];
    const float* h0     = (const float*)d_in[1];
    const float* c0     = (const float*)d_in[2];
    const float* w_ih_f = (const float*)d_in[3];
    const float* w_hh_f = (const float*)d_in[4];
    const float* b_f    = (const float*)d_in[5];
    const float* w_ih_b = (const float*)d_in[6];
    const float* w_hh_b = (const float*)d_in[7];
    const float* b_b    = (const float*)d_in[8];
    const float* w_lin  = (const float*)d_in[9];
    const float* b_lin  = (const float*)d_in[10];
    float* out = (float*)d_out;

    int B = in_sizes[1] / 16;   // h0: (2, B, 8)
    int T = in_sizes[0] / B;    // x:  (B, T, 1)

    int threads = B * 8;
    dim3 block(256);
    dim3 grid((threads + 255) / 256);
    hipLaunchKernelGGL(bilstm_kernel, grid, block, 0, stream,
                       x, h0, c0, w_ih_f, w_hh_f, b_f, w_ih_b, w_hh_b, b_b,
                       w_lin, b_lin, out, B, T);
}